// Round 3
// baseline (255.052 us; speedup 1.0000x reference)
//
#include <hip/hip_runtime.h>

#define DIMC 256
#define RTOT 1024
#define NE 64
#define NSLOT 1024
#define RC 256     // r-columns handled per block (grid.x = RTOT/RC = 4)
#define TILE 16    // slots per tile per block (half of the expert's slots)
#define SG 4       // slots per slot-group (4 waves x 4 slots = 16)

// ---------------- bucket slots by expert ----------------
__global__ __launch_bounds__(1024) void bucket_kernel(
    const int* __restrict__ idx, int* __restrict__ count,
    int* __restrict__ start, int* __restrict__ list) {
  __shared__ int cnt[NE];
  __shared__ int offs[NE];
  __shared__ int cur[NE];
  int t = threadIdx.x;
  if (t < NE) cnt[t] = 0;
  __syncthreads();
  int e = idx[t] & (NE - 1);
  atomicAdd(&cnt[e], 1);
  __syncthreads();
  if (t == 0) {
    int acc = 0;
    for (int i = 0; i < NE; ++i) { offs[i] = acc; cur[i] = acc; acc += cnt[i]; }
  }
  __syncthreads();
  if (t < NE) { count[t] = cnt[t]; start[t] = offs[t]; }
  int pos = atomicAdd(&cur[e], 1);
  list[pos] = t;
}

static __device__ __forceinline__ float4 f4ma(float a, float4 w, float4 c) {
  c.x = fmaf(a, w.x, c.x);
  c.y = fmaf(a, w.y, c.y);
  c.z = fmaf(a, w.z, c.z);
  c.w = fmaf(a, w.w, c.w);
  return c;
}

// ---------------- fused 2-layer expert MLP ----------------
// grid: (4 r-chunks, 64 experts, 2 slot-halves), block: 256 threads = 4 waves.
// Lane group g4 = t&63 owns 4 consecutive r (L1) / 4 consecutive d (L2);
// wave sg = t>>6 owns 4 slots. Slot-half z takes expert slots z, z+2, z+4, ...
// (interleaved -> balanced). 512 blocks = 2 blocks/CU = 8 waves/CU.
__global__ __launch_bounds__(256) void mlp_kernel(
    const float* __restrict__ slots, const float* __restrict__ w1,
    const float* __restrict__ b1, const float* __restrict__ w2,
    const float* __restrict__ b2, const int* __restrict__ count,
    const int* __restrict__ start, const int* __restrict__ list,
    float* __restrict__ out) {
  const int rc   = blockIdx.x;  // 0..3
  const int e    = blockIdx.y;  // 0..63
  const int half = blockIdx.z;  // 0..1
  const int n = count[e];
  const int nh = (n + 1 - half) >> 1;  // slots in this half
  if (nh <= 0) return;
  const int t  = threadIdx.x;
  const int g4 = t & 63;       // 64 groups of 4 columns
  const int sg = t >> 6;       // slot group 0..3
  const int rbase = rc * RC;

  __shared__ float xs[TILE][DIMC];  // x tile during L1, h tile during L2
  __shared__ int sid[TILE];

  const float* pw1 = w1 + (size_t)e * DIMC * RTOT + rbase + g4 * 4;   // stride RTOT per d
  const float* pw2 = w2 + ((size_t)e * RTOT + rbase) * DIMC + g4 * 4; // stride DIMC per r

  float4 b1v = *(const float4*)&b1[e * RTOT + rbase + g4 * 4];
  float4 b2v = (rc == 0) ? *(const float4*)&b2[e * DIMC + g4 * 4]
                         : make_float4(0.f, 0.f, 0.f, 0.f);
  const int st = start[e];

  for (int s0 = 0; s0 < nh; s0 += TILE) {
    const int m = (nh - s0 < TILE) ? (nh - s0) : TILE;

    __syncthreads();  // prior tile fully consumed before overwriting sid/xs
    if (t < TILE) {
      int ii = (t < m) ? t : (m - 1);
      sid[t] = list[st + half + 2 * (s0 + ii)];
    }
    __syncthreads();

    // load x tile (TILE x 256 floats) via float4, coalesced
    for (int i = t; i < TILE * (DIMC / 4); i += 256) {
      int s = i >> 6, d4 = i & 63;
      *(float4*)&xs[s][d4 * 4] =
          ((const float4*)slots)[(size_t)sid[s] * (DIMC / 4) + d4];
    }
    __syncthreads();

    // ---- layer 1: acc[s][0..3] = b1 + sum_d x[s][d] * w1[d][r4..r4+3]
    float4 acc[SG];
#pragma unroll
    for (int s = 0; s < SG; ++s) acc[s] = b1v;

#pragma unroll 8
    for (int d = 0; d < DIMC; d += 4) {
      float4 wA = *(const float4*)(pw1 + (size_t)(d + 0) * RTOT);
      float4 wB = *(const float4*)(pw1 + (size_t)(d + 1) * RTOT);
      float4 wC = *(const float4*)(pw1 + (size_t)(d + 2) * RTOT);
      float4 wD = *(const float4*)(pw1 + (size_t)(d + 3) * RTOT);
#pragma unroll
      for (int s = 0; s < SG; ++s) {
        float4 xv = *(const float4*)&xs[sg * SG + s][d];  // LDS broadcast
        acc[s] = f4ma(xv.x, wA, acc[s]);
        acc[s] = f4ma(xv.y, wB, acc[s]);
        acc[s] = f4ma(xv.z, wC, acc[s]);
        acc[s] = f4ma(xv.w, wD, acc[s]);
      }
    }
    __syncthreads();  // all x reads done; reuse xs for h

    // relu -> h tile
#pragma unroll
    for (int s = 0; s < SG; ++s) {
      float4 h;
      h.x = fmaxf(acc[s].x, 0.f);
      h.y = fmaxf(acc[s].y, 0.f);
      h.z = fmaxf(acc[s].z, 0.f);
      h.w = fmaxf(acc[s].w, 0.f);
      *(float4*)&xs[sg * SG + s][g4 * 4] = h;
    }
    __syncthreads();

    // ---- layer 2 partial: o[s][0..3] = b2 + sum_{r in chunk} h[s][r] * w2[r][d4..d4+3]
    float4 o[SG];
#pragma unroll
    for (int s = 0; s < SG; ++s) o[s] = b2v;

#pragma unroll 8
    for (int r = 0; r < RC; r += 4) {
      float4 wA = *(const float4*)(pw2 + (size_t)(r + 0) * DIMC);
      float4 wB = *(const float4*)(pw2 + (size_t)(r + 1) * DIMC);
      float4 wC = *(const float4*)(pw2 + (size_t)(r + 2) * DIMC);
      float4 wD = *(const float4*)(pw2 + (size_t)(r + 3) * DIMC);
#pragma unroll
      for (int s = 0; s < SG; ++s) {
        float4 hv = *(const float4*)&xs[sg * SG + s][r];  // LDS broadcast
        o[s] = f4ma(hv.x, wA, o[s]);
        o[s] = f4ma(hv.y, wB, o[s]);
        o[s] = f4ma(hv.z, wC, o[s]);
        o[s] = f4ma(hv.w, wD, o[s]);
      }
    }

    for (int s = 0; s < SG; ++s) {
      int ss = sg * SG + s;
      if (ss < m) {
        float* po = &out[(size_t)sid[ss] * DIMC + g4 * 4];
        atomicAdd(po + 0, o[s].x);
        atomicAdd(po + 1, o[s].y);
        atomicAdd(po + 2, o[s].z);
        atomicAdd(po + 3, o[s].w);
      }
    }
  }
}

extern "C" void kernel_launch(void* const* d_in, const int* in_sizes, int n_in,
                              void* d_out, int out_size, void* d_ws, size_t ws_size,
                              hipStream_t stream) {
  const float* slots   = (const float*)d_in[0];
  const float* w1      = (const float*)d_in[1];
  const float* b1      = (const float*)d_in[2];
  const float* w2      = (const float*)d_in[3];
  const float* b2      = (const float*)d_in[4];
  const int*   indices = (const int*)d_in[5];
  float* out = (float*)d_out;

  int* ws    = (int*)d_ws;
  int* count = ws;         // 64
  int* start = ws + 64;    // 64
  int* list  = ws + 128;   // 1024

  hipMemsetAsync(d_out, 0, (size_t)out_size * sizeof(float), stream);
  bucket_kernel<<<1, NSLOT, 0, stream>>>(indices, count, start, list);
  mlp_kernel<<<dim3(4, NE, 2), 256, 0, stream>>>(slots, w1, b1, w2, b2,
                                                 count, start, list, out);
}

// Round 4
// 184.157 us; speedup vs baseline: 1.3850x; 1.3850x over previous
//
#include <hip/hip_runtime.h>
#include <stdint.h>

#define DIMC 256
#define RTOT 1024
#define NE 64
#define NSLOT 1024
#define RC 256     // r-columns per block (grid.x = 4)
#define TILE 32    // slots per pass (covers max expert load in one pass)
#define SG 8       // slots per wave (4 waves x 8 = 32)
#define DT 32      // weight rows per staged tile
#define NT 16      // 8 w1 tiles + 8 w2 tiles

typedef const __attribute__((address_space(1))) void* gptr_t;
typedef __attribute__((address_space(3))) void* lptr_t;

// ---------------- bucket slots by expert ----------------
__global__ __launch_bounds__(1024) void bucket_kernel(
    const int* __restrict__ idx, int* __restrict__ count,
    int* __restrict__ start, int* __restrict__ list) {
  __shared__ int cnt[NE];
  __shared__ int offs[NE];
  __shared__ int cur[NE];
  int t = threadIdx.x;
  if (t < NE) cnt[t] = 0;
  __syncthreads();
  int e = idx[t] & (NE - 1);
  atomicAdd(&cnt[e], 1);
  __syncthreads();
  if (t == 0) {
    int acc = 0;
    for (int i = 0; i < NE; ++i) { offs[i] = acc; cur[i] = acc; acc += cnt[i]; }
  }
  __syncthreads();
  if (t < NE) { count[t] = cnt[t]; start[t] = offs[t]; }
  int pos = atomicAdd(&cur[e], 1);
  list[pos] = t;
}

static __device__ __forceinline__ float4 f4ma(float a, float4 w, float4 c) {
  c.x = fmaf(a, w.x, c.x);
  c.y = fmaf(a, w.y, c.y);
  c.z = fmaf(a, w.z, c.z);
  c.w = fmaf(a, w.w, c.w);
  return c;
}

// ---------------- fused 2-layer expert MLP ----------------
// grid: (4 r-chunks, 64 experts), 256 threads = 4 waves, 1 block/CU.
// Weights stream global->LDS ONCE per CU via async global_load_lds (width 16),
// double-buffered DT-row tiles. Waves consume weights from LDS (b128, minimal
// spread) and x/h via same-address LDS broadcasts. No duplication anywhere.
__global__ __launch_bounds__(256) void mlp_kernel(
    const float* __restrict__ slots, const float* __restrict__ w1,
    const float* __restrict__ b1, const float* __restrict__ w2,
    const float* __restrict__ b2, const int* __restrict__ count,
    const int* __restrict__ start, const int* __restrict__ list,
    float* __restrict__ out) {
  const int rc = blockIdx.x;   // 0..3
  const int e  = blockIdx.y;   // 0..63
  const int n  = count[e];
  if (n == 0) return;
  const int t  = threadIdx.x;
  const int g4 = t & 63;       // lane's 4-column group
  const int w  = t >> 6;       // wave 0..3
  const int rbase = rc * RC;

  __shared__ float xs[TILE][DIMC];     // x tile during L1, h tile during L2
  __shared__ float wt[2][DT][DIMC];    // double-buffered staged weight tiles
  __shared__ int   sid[TILE];

  // per-lane source pointers (lane offset g4*4 -> DMA lane order = 16B*lane)
  const float* w1e = w1 + (size_t)e * DIMC * RTOT + rbase + g4 * 4;   // + d*RTOT
  const float* w2e = w2 + ((size_t)e * RTOT + rbase) * DIMC + g4 * 4; // + r*DIMC

  const float4 b1v = *(const float4*)&b1[e * RTOT + rbase + g4 * 4];
  const float4 b2v = (rc == 0) ? *(const float4*)&b2[e * DIMC + g4 * 4]
                               : make_float4(0.f, 0.f, 0.f, 0.f);
  const int st = start[e];

  for (int s0 = 0; s0 < n; s0 += TILE) {
    const int m = (n - s0 < TILE) ? (n - s0) : TILE;

    __syncthreads();  // prior pass fully done before overwriting sid/xs
    if (t < TILE) sid[t] = list[st + s0 + ((t < m) ? t : (m - 1))];
    __syncthreads();

    // stage w1 tile 0 (async DMA) ...
#pragma unroll
    for (int j = 0; j < DT / 4; ++j) {
      int row = w * (DT / 4) + j;  // wave w stages rows w*8..w*8+7
      __builtin_amdgcn_global_load_lds((gptr_t)(w1e + (size_t)row * RTOT),
                                       (lptr_t)&wt[0][row][0], 16, 0, 0);
    }
    // ... while loading the x tile with regular vector loads
    for (int i = t; i < TILE * (DIMC / 4); i += 256) {
      int s = i >> 6, d4 = i & 63;
      *(float4*)&xs[s][d4 * 4] =
          ((const float4*)slots)[(size_t)sid[s] * (DIMC / 4) + d4];
    }
    __syncthreads();  // drains x loads + tile-0 DMA (vmcnt(0) at barrier)

    float4 acc[SG];
#pragma unroll
    for (int s = 0; s < SG; ++s) acc[s] = b1v;

    for (int k = 0; k < NT; ++k) {
      const int buf = k & 1;

      // issue next tile's DMA into the other buffer (overlaps this compute)
      if (k + 1 < NT) {
        const int kn = k + 1;
        const float* src = (kn < 8) ? (w1e + (size_t)(kn * DT) * RTOT)
                                    : (w2e + (size_t)((kn - 8) * DT) * DIMC);
        const size_t rstride = (kn < 8) ? RTOT : DIMC;
#pragma unroll
        for (int j = 0; j < DT / 4; ++j) {
          int row = w * (DT / 4) + j;
          __builtin_amdgcn_global_load_lds((gptr_t)(src + (size_t)row * rstride),
                                           (lptr_t)&wt[buf ^ 1][row][0], 16, 0, 0);
        }
      }

      if (k == 8) {
        // L1 -> L2 transition: all x reads finished at k=7's barrier.
        // Write relu(h) into xs, re-init acc with b2.
#pragma unroll
        for (int s = 0; s < SG; ++s) {
          float4 h = acc[s];
          h.x = fmaxf(h.x, 0.f); h.y = fmaxf(h.y, 0.f);
          h.z = fmaxf(h.z, 0.f); h.w = fmaxf(h.w, 0.f);
          *(float4*)&xs[w * SG + s][g4 * 4] = h;
          acc[s] = b2v;
        }
        __syncthreads();
      }

      // compute tile k from wt[buf]; x/h local offset identical for both layers
      const int xoff = (k < 8 ? k : k - 8) * DT;
#pragma unroll
      for (int dg = 0; dg < DT / 4; ++dg) {
        float4 wA = *(const float4*)&wt[buf][dg * 4 + 0][g4 * 4];
        float4 wB = *(const float4*)&wt[buf][dg * 4 + 1][g4 * 4];
        float4 wC = *(const float4*)&wt[buf][dg * 4 + 2][g4 * 4];
        float4 wD = *(const float4*)&wt[buf][dg * 4 + 3][g4 * 4];
#pragma unroll
        for (int s = 0; s < SG; ++s) {
          float4 xv = *(const float4*)&xs[w * SG + s][xoff + dg * 4];  // broadcast
          acc[s] = f4ma(xv.x, wA, acc[s]);
          acc[s] = f4ma(xv.y, wB, acc[s]);
          acc[s] = f4ma(xv.z, wC, acc[s]);
          acc[s] = f4ma(xv.w, wD, acc[s]);
        }
      }
      __syncthreads();  // tile k consumed by all waves; next DMA drained
    }

    // epilogue: acc holds this block's partial output
#pragma unroll
    for (int s = 0; s < SG; ++s) {
      int ss = w * SG + s;
      if (ss < m) {
        float* po = &out[(size_t)sid[ss] * DIMC + g4 * 4];
        atomicAdd(po + 0, acc[s].x);
        atomicAdd(po + 1, acc[s].y);
        atomicAdd(po + 2, acc[s].z);
        atomicAdd(po + 3, acc[s].w);
      }
    }
  }
}

extern "C" void kernel_launch(void* const* d_in, const int* in_sizes, int n_in,
                              void* d_out, int out_size, void* d_ws, size_t ws_size,
                              hipStream_t stream) {
  const float* slots   = (const float*)d_in[0];
  const float* w1      = (const float*)d_in[1];
  const float* b1      = (const float*)d_in[2];
  const float* w2      = (const float*)d_in[3];
  const float* b2      = (const float*)d_in[4];
  const int*   indices = (const int*)d_in[5];
  float* out = (float*)d_out;

  int* ws    = (int*)d_ws;
  int* count = ws;         // 64
  int* start = ws + 64;    // 64
  int* list  = ws + 128;   // 1024

  hipMemsetAsync(d_out, 0, (size_t)out_size * sizeof(float), stream);
  bucket_kernel<<<1, NSLOT, 0, stream>>>(indices, count, start, list);
  mlp_kernel<<<dim3(4, NE), 256, 0, stream>>>(slots, w1, b1, w2, b2,
                                              count, start, list, out);
}